// Round 1
// baseline (260.863 us; speedup 1.0000x reference)
//
#include <hip/hip_runtime.h>

// out[v,g,u,d] = W[GE[v,g] % 3, d] + b[d], out shape [V=512, G=4, V=512, D=64] fp32.
// Pure write-BW bound: 256 MiB of stores, ~8 KB of reads.
//
// v2 theory: the previous per-(v,g)-block layout created 2048 phase-aligned
// write streams at a 128 KiB power-of-2 stride (every block starts at offset 0
// of its chunk at t=0) -> HBM channel aliasing, ~2.9 TB/s effective.
// rocclr fillBuffer on this same device/buffer measures 6.58 TB/s with a
// linear sweep. This version reproduces the fill's access pattern exactly:
// one dense grid-stride sweep over the whole 256 MiB output.
//
// Index math (all exact, no bounds checks needed):
//   i  = bid*256 + tid + k*524288      (float4 index, k = 0..31)
//   d4 = i & 15  == tid & 15           (stride and block base are mult. of 16)
//   vg = i >> 13 == (bid >> 5) + 64*k  (block-uniform -> scalar load of GE)

#define V 512
#define G 4
#define D 64
#define D4 (D / 4)          // 16 float4 per D-row
#define NBLK 2048
#define NTHR 256
#define SWEEP ((size_t)NBLK * NTHR)   // 524288 float4 per sweep (8 MiB)
#define NITER 32                      // 2048*512*16 / 524288

__global__ __launch_bounds__(NTHR) void gembed_kernel(
    const int* __restrict__ GE,      // [V*G] int32, values in [0,3)
    const float* __restrict__ W,     // [3, D]
    const float* __restrict__ b,     // [D]
    float* __restrict__ out)         // [V*G*V*D]
{
    const int bid = blockIdx.x;
    const int tid = threadIdx.x;
    const int d4  = tid & (D4 - 1);

    const float4* __restrict__ W4 = (const float4*)W;  // [3 * D4]
    const float4* __restrict__ b4 = (const float4*)b;  // [D4]

    // Precompute the three candidate row-values for this thread's d4 slot.
    const float4 bb = b4[d4];
    const float4 w0 = W4[0 * D4 + d4];
    const float4 w1 = W4[1 * D4 + d4];
    const float4 w2 = W4[2 * D4 + d4];

    float4 v0, v1, v2;
    v0.x = w0.x + bb.x; v0.y = w0.y + bb.y; v0.z = w0.z + bb.z; v0.w = w0.w + bb.w;
    v1.x = w1.x + bb.x; v1.y = w1.y + bb.y; v1.z = w1.z + bb.z; v1.w = w1.w + bb.w;
    v2.x = w2.x + bb.x; v2.y = w2.y + bb.y; v2.z = w2.z + bb.z; v2.w = w2.w + bb.w;

    // Linear sweep: identical store-address shape to fillBuffer.
    float4* __restrict__ p = (float4*)out + ((size_t)bid * NTHR + tid);
    int vg = bid >> 5;   // block-uniform; advances by 64 per sweep

    #pragma unroll 8
    for (int k = 0; k < NITER; ++k) {
        const int e = GE[vg];        // wave-uniform -> scalar load, L1-resident
        float4 v;
        v.x = (e == 0) ? v0.x : ((e == 1) ? v1.x : v2.x);
        v.y = (e == 0) ? v0.y : ((e == 1) ? v1.y : v2.y);
        v.z = (e == 0) ? v0.z : ((e == 1) ? v1.z : v2.z);
        v.w = (e == 0) ? v0.w : ((e == 1) ? v1.w : v2.w);
        *p = v;
        p  += SWEEP;
        vg += 64;
    }
}

extern "C" void kernel_launch(void* const* d_in, const int* in_sizes, int n_in,
                              void* d_out, int out_size, void* d_ws, size_t ws_size,
                              hipStream_t stream) {
    const int*   GE = (const int*)d_in[0];
    const float* W  = (const float*)d_in[1];
    const float* b  = (const float*)d_in[2];
    float* out = (float*)d_out;

    gembed_kernel<<<NBLK, NTHR, 0, stream>>>(GE, W, b, out);
}